// Round 12
// baseline (183.858 us; speedup 1.0000x reference)
//
#include <hip/hip_runtime.h>
#include <stdint.h>

#define CIN 256
#define COUT 256
#define RANK 64
#define H_ 112
#define W_ 112
#define HW_ (112*112)

typedef short bf16x8 __attribute__((ext_vector_type(8)));   // 8 bf16 = 4 VGPRs
typedef float f32x4 __attribute__((ext_vector_type(4)));

// round-to-nearest-even fp32 -> bf16, packed pair
__device__ __forceinline__ unsigned rne2(float a, float b){
  unsigned ua = __builtin_bit_cast(unsigned, a);
  unsigned ub = __builtin_bit_cast(unsigned, b);
  ua += 0x7FFFu + ((ua >> 16) & 1u);
  ub += 0x7FFFu + ((ub >> 16) & 1u);
  return (ua >> 16) | (ub & 0xFFFF0000u);
}
__device__ __forceinline__ unsigned short rne1(float a){
  unsigned ua = __builtin_bit_cast(unsigned, a);
  ua += 0x7FFFu + ((ua >> 16) & 1u);
  return (unsigned short)(ua >> 16);
}

// ---- K_pre1: blocks [0, nb*114): x NCHW fp32 -> xt bf16 [lb][hh=114][i0=8][g=4][w=112][c=8]
//              blocks [nb*114, +256): w_sum[o][i] = sum_k w_head[k][o][i]  (chunk 0 only)
__global__ __launch_bounds__(256) void k_pre1(const float* __restrict__ x,
                                              unsigned short* __restrict__ xt,
                                              const float* __restrict__ wh,
                                              float* __restrict__ wsum,
                                              int base_b, int nb){
  __shared__ float ldsf[64*120];
  const int tid = threadIdx.x;
  if (blockIdx.x >= (unsigned)(nb*114)){
    int o = blockIdx.x - nb*114;
    float s = 0.f;
    for (int k = 0; k < RANK; ++k) s += wh[(k*COUT + o)*CIN + tid];
    wsum[o*CIN + tid] = s;
    return;
  }
  const int lb = blockIdx.x / 114, hh = blockIdx.x % 114;
  const int bb = base_b + lb;
  const int h = hh - 1;
  unsigned short* dst = xt + ((size_t)(lb*114 + hh))*28672;

  if (h < 0 || h >= H_){
    uint4 z = {0,0,0,0};
    #pragma unroll
    for (int j = 0; j < 14; ++j)
      *(uint4*)(dst + (tid + 256*j)*8) = z;
    return;
  }

  for (int i0p = 0; i0p < 4; ++i0p){   // 64 channels per pass
    int c = tid / 28, wq = tid % 28;
    #pragma unroll
    for (int j = 0; j < 7; ++j){
      const float4 v = *(const float4*)(x + ((size_t)(bb*CIN + i0p*64 + c))*HW_ + h*W_ + wq*4);
      *(float4*)&ldsf[c*120 + wq*4] = v;
      wq += 4; c += 9; if (wq >= 28){ wq -= 28; c += 1; }
    }
    __syncthreads();
    for (int ck = tid; ck < 896; ck += 256){
      int g8 = ck / 112, w = ck % 112;
      const float* src = &ldsf[(g8*8)*120 + w];
      uint4 st;
      st.x = rne2(src[0],     src[120]);
      st.y = rne2(src[240],   src[360]);
      st.z = rne2(src[480],   src[600]);
      st.w = rne2(src[720],   src[840]);
      *(uint4*)(dst + (size_t)(i0p*896 + ck)*8) = st;
    }
    __syncthreads();
  }
}

// ---- K_pre2: blocks [0,192): w_eff[dh][r][i] (bf16); blocks [192,448): wtp[o][dw][r] (bf16)
__global__ __launch_bounds__(256) void k_pre2(const float* __restrict__ wb,
                                              const float* __restrict__ wsum,
                                              unsigned short* __restrict__ weff,
                                              const float* __restrict__ wt,
                                              unsigned short* __restrict__ wtp){
  const int tid = threadIdx.x;
  if (blockIdx.x < 192){
    int bid = blockIdx.x;            // dh*64 + r
    int dh = bid >> 6, r = bid & 63;
    float s = 0.f;
    for (int o = 0; o < COUT; ++o)
      s += wb[(r*COUT + o)*3 + dh] * wsum[o*CIN + tid];
    weff[bid*CIN + tid] = rne1(s);
  } else {
    int o = blockIdx.x - 192;
    if (tid < 192){
      int dw = tid >> 6, r = tid & 63;
      wtp[o*192 + tid] = rne1(wt[(o*RANK + r)*3 + dw]);
    }
  }
}

// ---- K_fused: body GEMM (depth-2 pipelined staging) -> LDS y2 -> tail GEMM -> out ----
// Grid: nb*56 blocks (lb, h-pair), 256 threads / 4 waves.
// Phase A: 16 half-quanta (q = i0*2 + whalf), 3 LDS buffers of 16384 B, TWO stages
//   in flight across every compute (T3/T4); one vmcnt(4)+s_barrier per step.
//   weff A-frags loaded once per i0, hoisted BEFORE the stage issue (in-order
//   vmcnt retirement must never drain the prefetch — R9 lesson).
// Phase C: 4 o-passes of 32 (a2[2][7]).
__global__ __launch_bounds__(256,3) void k_fused(const unsigned short* __restrict__ xt,
                                                 const unsigned short* __restrict__ weff,
                                                 const unsigned short* __restrict__ wtp,
                                                 const float* __restrict__ bias,
                                                 float* __restrict__ out,
                                                 int base_b){
  __shared__ alignas(16) unsigned short lds[24576];  // 49152 B: 3 x 16384 B stage bufs
  const int tid  = threadIdx.x;
  const int wid  = tid >> 6, lane = tid & 63, g = lane >> 4, l15 = lane & 15;
  const int lb   = blockIdx.x / 56, hb = blockIdx.x % 56;
  const int bb   = base_b + lb;
  const int h0   = hb*2;
  const int hloc = wid >> 1, rhalf = wid & 1;

  // ---- phase A: body GEMM, 16 quanta, depth-2 pipeline ----
  f32x4 acc[2][7];
  #pragma unroll
  for (int a = 0; a < 2; ++a)
    #pragma unroll
    for (int b = 0; b < 7; ++b) acc[a][b] = (f32x4){0.f,0.f,0.f,0.f};

  const unsigned short* rowbase = xt + ((size_t)(lb*114 + h0 + wid)*8)*3584;

  // stage quantum q: wave wid stages its row. half0 = [4g][w0..63][c8] (4096B/row),
  // half1 = [4g][w64..111][c8] (3072B/row). dst wave-uniform; src per-lane. 4 vm ops.
  auto stage = [&](unsigned short* dstbuf, int q){
    const int i0 = q >> 1, hf = q & 1;
    const unsigned short* src0 = rowbase + (size_t)i0*3584;
    if (hf == 0){
      unsigned short* dstb = dstbuf + wid*2048;
      const unsigned short* s = src0 + lane*8;
      #pragma unroll
      for (int gc = 0; gc < 4; ++gc)
        __builtin_amdgcn_global_load_lds(
          (const __attribute__((address_space(1))) void*)(s + gc*896),
          (__attribute__((address_space(3))) void*)(dstb + gc*512), 16, 0, 0);
    } else {
      if (lane < 48){
        unsigned short* dstb = dstbuf + wid*1536;
        const unsigned short* s = src0 + 512 + lane*8;
        #pragma unroll
        for (int gc = 0; gc < 4; ++gc)
          __builtin_amdgcn_global_load_lds(
            (const __attribute__((address_space(1))) void*)(s + gc*896),
            (__attribute__((address_space(3))) void*)(dstb + gc*384), 16, 0, 0);
      }
    }
  };

  bf16x8 af0[3], af1[3];             // weff A-frags, persist across the hf-pair
  auto loadA = [&](int i0){
    #pragma unroll
    for (int dh = 0; dh < 3; ++dh){
      const unsigned short* ab = weff + (size_t)(dh*64 + rhalf*32 + l15)*CIN + i0*32 + g*8;
      af0[dh] = *(const bf16x8*)(ab);
      af1[dh] = *(const bf16x8*)(ab + 16*CIN);
    }
  };

  auto mstep = [&](const unsigned short* buf, int q){
    const int hf = q & 1;
    const int wt0 = hf ? 4 : 0, wtn = hf ? 3 : 4;
    const int rstride = hf ? 1536 : 2048;
    const int gstride = hf ? 384 : 512;
    #pragma unroll
    for (int dh = 0; dh < 3; ++dh){
      const unsigned short* qb = buf + (hloc + dh)*rstride + g*gstride + l15*8;
      #pragma unroll
      for (int w = 0; w < 4; ++w){
        if (w < wtn){
          bf16x8 bfv = *(const bf16x8*)(qb + w*128);
          acc[0][wt0+w] = __builtin_amdgcn_mfma_f32_16x16x32_bf16(af0[dh], bfv, acc[0][wt0+w], 0, 0, 0);
          acc[1][wt0+w] = __builtin_amdgcn_mfma_f32_16x16x32_bf16(af1[dh], bfv, acc[1][wt0+w], 0, 0, 0);
        }
      }
    }
  };

  unsigned short* const bufs[3] = {lds, lds + 8192, lds + 16384};
  stage(bufs[0], 0);
  stage(bufs[1], 1);
  #pragma unroll
  for (int q = 0; q < 16; ++q){
    // stage(q) complete (<=4 outstanding = only stage(q+1)); then rendezvous
    if (q < 15) asm volatile("s_waitcnt vmcnt(4)" ::: "memory");
    else        asm volatile("s_waitcnt vmcnt(0)" ::: "memory");
    __builtin_amdgcn_s_barrier();
    __builtin_amdgcn_sched_barrier(0);
    if ((q & 1) == 0) loadA(q >> 1);     // weff loads BEFORE stage issue (in-order!)
    if (q < 14) stage(bufs[(q + 2) % 3], q + 2);
    mstep(bufs[q % 3], q);
  }
  asm volatile("s_waitcnt vmcnt(0)" ::: "memory");
  __builtin_amdgcn_s_barrier();          // buffers free before slab overlays them

  // ---- phase B: acc -> LDS y2 slab [2 h][114 w'][72 pad] (bf16), w' = w+1 ----
  unsigned short* y2b = lds;
  if (tid < 32){
    int hh = tid >> 4, wsel = (tid >> 3) & 1, rq = tid & 7;
    *(uint4*)(y2b + hh*8208 + (wsel ? 113 : 0)*72 + rq*8) = (uint4){0,0,0,0};
  }
  #pragma unroll
  for (int wt = 0; wt < 7; ++wt){
    #pragma unroll
    for (int rt = 0; rt < 2; ++rt){
      unsigned lo = rne2(acc[rt][wt][0], acc[rt][wt][1]);
      unsigned hi = rne2(acc[rt][wt][2], acc[rt][wt][3]);
      uint2 st; st.x = lo; st.y = hi;
      *(uint2*)(y2b + hloc*8208 + (wt*16 + l15 + 1)*72 + rhalf*32 + rt*16 + g*4) = st;
    }
  }
  __syncthreads();

  // ---- phase C: tail GEMM, 4 passes of 32 o per wave (56 acc regs/pass) ----
  const int h = h0 + hloc;
  #pragma unroll
  for (int opass = 0; opass < 4; ++opass){
    const int obase = rhalf*128 + opass*32;
    f32x4 a2[2][7];
    #pragma unroll
    for (int a = 0; a < 2; ++a)
      #pragma unroll
      for (int b = 0; b < 7; ++b) a2[a][b] = (f32x4){0.f,0.f,0.f,0.f};

    #pragma unroll
    for (int s = 0; s < 6; ++s){       // k-step: dw = s>>1, r-half = s&1
      bf16x8 afc[2];
      const unsigned short* ab = wtp + (size_t)(obase + l15)*192 + s*32 + g*8;
      #pragma unroll
      for (int rt = 0; rt < 2; ++rt)
        afc[rt] = *(const bf16x8*)(ab + rt*16*192);
      const unsigned short* qb = y2b + hloc*8208 + (l15 + (s >> 1))*72 + (s & 1)*32 + g*8;
      #pragma unroll
      for (int wt = 0; wt < 7; ++wt){
        bf16x8 bv = *(const bf16x8*)(qb + wt*16*72);
        #pragma unroll
        for (int rt = 0; rt < 2; ++rt)
          a2[rt][wt] = __builtin_amdgcn_mfma_f32_16x16x32_bf16(afc[rt], bv, a2[rt][wt], 0, 0, 0);
      }
    }

    float* ob = out + ((size_t)(bb*COUT) + obase)*HW_ + h*W_;
    #pragma unroll
    for (int rt = 0; rt < 2; ++rt){
      #pragma unroll
      for (int ii = 0; ii < 4; ++ii){
        float bvv = bias[obase + rt*16 + g*4 + ii];
        #pragma unroll
        for (int wt = 0; wt < 7; ++wt)
          ob[(size_t)(rt*16 + g*4 + ii)*HW_ + wt*16 + l15] = a2[rt][wt][ii] + bvv;
      }
    }
  }
}

extern "C" void kernel_launch(void* const* d_in, const int* in_sizes, int n_in,
                              void* d_out, int out_size, void* d_ws, size_t ws_size,
                              hipStream_t stream) {
  const float* x      = (const float*)d_in[0];
  const float* w_head = (const float*)d_in[1];
  const float* w_body = (const float*)d_in[2];
  const float* w_tail = (const float*)d_in[3];
  const float* b_tail = (const float*)d_in[4];
  float* out = (float*)d_out;
  char* ws = (char*)d_ws;

  // ws layout: wsum fp32 @0 (262144 B); weff bf16 @262144 (98304 B);
  // wtp bf16 @360448 (98304 B); xt chunk buffer @458752.
  float*          wsum = (float*)ws;
  unsigned short* weff = (unsigned short*)(ws + 262144);
  unsigned short* wtp  = (unsigned short*)(ws + 360448);
  unsigned short* xt   = (unsigned short*)(ws + 458752);

  const size_t XT_PER_B = (size_t)114 * 57344;           // 6,537,216 B per batch
  size_t avail = (ws_size > 458752) ? ws_size - 458752 : 0;
  int chunk_b = (int)(avail / XT_PER_B);
  if (chunk_b > 16) chunk_b = 16;
  if (chunk_b < 1)  chunk_b = 1;                         // ws proven >= 26.1 MB, so >= 3
  int nchunks = (16 + chunk_b - 1) / chunk_b;

  int base = 0;
  for (int c = 0; c < nchunks; ++c){
    int remaining = 16 - base;
    int nb = (remaining + (nchunks - c) - 1) / (nchunks - c);   // balanced split
    k_pre1<<<nb*114 + (c == 0 ? 256 : 0), 256, 0, stream>>>(x, xt, w_head, wsum, base, nb);
    if (c == 0)
      k_pre2<<<448, 256, 0, stream>>>(w_body, wsum, weff, w_tail, wtp);
    k_fused<<<nb*56, 256, 0, stream>>>(xt, weff, wtp, b_tail, out, base);
    base += nb;
  }
}

// Round 13
// 162.378 us; speedup vs baseline: 1.1323x; 1.1323x over previous
//
#include <hip/hip_runtime.h>
#include <stdint.h>

#define CIN 256
#define COUT 256
#define RANK 64
#define H_ 112
#define W_ 112
#define HW_ (112*112)

typedef short bf16x8 __attribute__((ext_vector_type(8)));   // 8 bf16 = 4 VGPRs
typedef float f32x4 __attribute__((ext_vector_type(4)));

// round-to-nearest-even fp32 -> bf16, packed pair (a -> low, b -> high)
__device__ __forceinline__ unsigned rne2(float a, float b){
  unsigned ua = __builtin_bit_cast(unsigned, a);
  unsigned ub = __builtin_bit_cast(unsigned, b);
  ua += 0x7FFFu + ((ua >> 16) & 1u);
  ub += 0x7FFFu + ((ub >> 16) & 1u);
  return (ua >> 16) | (ub & 0xFFFF0000u);
}
__device__ __forceinline__ unsigned short rne1(float a){
  unsigned ua = __builtin_bit_cast(unsigned, a);
  ua += 0x7FFFu + ((ua >> 16) & 1u);
  return (unsigned short)(ua >> 16);
}

// ---- K0a: w_sum[o][i] = sum_k w_head[k][o][i] ----
__global__ __launch_bounds__(256) void k_wsum(const float* __restrict__ wh,
                                              float* __restrict__ wsum){
  int o = blockIdx.x, i = threadIdx.x;
  float s = 0.f;
  for (int k = 0; k < RANK; ++k) s += wh[(k*COUT + o)*CIN + i];
  wsum[o*CIN + i] = s;
}

// ---- K0b: blocks [0,192): w_eff[dh][r][i] (bf16); blocks [192,448): wtp[o][dw][r] (bf16)
__global__ __launch_bounds__(256) void k_pre2(const float* __restrict__ wb,
                                              const float* __restrict__ wsum,
                                              unsigned short* __restrict__ weff,
                                              const float* __restrict__ wt,
                                              unsigned short* __restrict__ wtp){
  const int tid = threadIdx.x;
  if (blockIdx.x < 192){
    int bid = blockIdx.x;            // dh*64 + r
    int dh = bid >> 6, r = bid & 63;
    float s = 0.f;
    for (int o = 0; o < COUT; ++o)
      s += wb[(r*COUT + o)*3 + dh] * wsum[o*CIN + tid];
    weff[bid*CIN + tid] = rne1(s);
  } else {
    int o = blockIdx.x - 192;
    if (tid < 192){
      int dw = tid >> 6, r = tid & 63;
      wtp[o*192 + tid] = rne1(wt[(o*RANK + r)*3 + dw]);
    }
  }
}

// ---- K_all: x fp32 -> in-kernel bf16 transpose-stage -> body GEMM -> LDS y2
//             -> tail GEMM -> out (fp32, NCHW). Single heavy kernel.
// Grid 896 = 16 b x 56 h-pairs, XCD-swizzled. 4 waves; wave wid stages global row
// h0-1+wid; computes hloc=wid>>1, rhalf=wid&1 (1 h x 32 r x 112 w in phase A).
// Stage chunk layout: [4 rows][4 g][112 w-slots][8 c] bf16, w stored at slot
// w ^ (g&3) (bank-conflict-free writes AND reads; weights unaffected since the
// c-order inside each 16B group is untouched).
__global__ __launch_bounds__(256,2) void k_all(const float* __restrict__ x,
                                               const unsigned short* __restrict__ weff,
                                               const unsigned short* __restrict__ wtp,
                                               const float* __restrict__ bias,
                                               float* __restrict__ out,
                                               unsigned cpx){
  __shared__ alignas(16) unsigned short lds[16416];  // 32832 B: stage (28672) / y2 slab
  const int tid  = threadIdx.x;
  const int wid  = tid >> 6, lane = tid & 63, g = lane >> 4, l15 = lane & 15;
  const unsigned orig = blockIdx.x;
  const unsigned wg   = (orig & 7u)*cpx + (orig >> 3);   // bijective XCD swizzle
  const int bb   = wg / 56, hb = wg % 56;
  const int h0   = hb*2;
  const int hloc = wid >> 1, rhalf = wid & 1;

  // staging lane roles: q = lane&3 (w-quad), cpair = lane>>2 (0..15)
  const int q_st  = lane & 3, cpair = lane >> 2;
  const int g_st  = cpair >> 2, cp3 = cpair & 3;
  const int grow  = h0 - 1 + wid;                      // global h of this wave's row
  const bool rok  = (grow >= 0) && (grow < H_);
  // x base for this wave's row, channel c0 = i0*32 + cpair*2
  const float* xrow = x + ((size_t)bb*CIN + cpair*2)*HW_ + (size_t)(rok ? grow : 0)*W_;
  unsigned char* const stg = (unsigned char*)lds;

  // ---- phase A: 8 chunks of 32 channels; reg-staged transpose, 1 LDS buffer ----
  f32x4 acc[2][7];
  #pragma unroll
  for (int a = 0; a < 2; ++a)
    #pragma unroll
    for (int b = 0; b < 7; ++b) acc[a][b] = (f32x4){0.f,0.f,0.f,0.f};

  f32x4 av[7], bv[7];                                  // in-flight load batch (56 VGPR)
  auto LOADS = [&](int i0){
    const float* pa = xrow + (size_t)i0*32*HW_;
    #pragma unroll
    for (int j = 0; j < 7; ++j){
      const int w0 = 16*j + q_st*4;
      if (rok){
        av[j] = *(const f32x4*)(pa + w0);
        bv[j] = *(const f32x4*)(pa + HW_ + w0);
      } else {
        av[j] = (f32x4){0.f,0.f,0.f,0.f};
        bv[j] = (f32x4){0.f,0.f,0.f,0.f};
      }
    }
  };
  auto WRITE = [&](){
    // dst byte: row*7168 + g*1792 + ((w)^(g&3))*16 + cp3*4
    unsigned char* base = stg + wid*7168 + g_st*1792 + cp3*4;
    #pragma unroll
    for (int j = 0; j < 7; ++j){
      const int w0 = 16*j + q_st*4;
      #pragma unroll
      for (int k = 0; k < 4; ++k){
        unsigned pk = rne2(av[j][k], bv[j][k]);
        *(unsigned*)(base + (unsigned)(((w0 + k) ^ (g_st & 3))*16)) = pk;
      }
    }
  };
  auto MSTEP = [&](int i0){
    #pragma unroll
    for (int dh = 0; dh < 3; ++dh){
      const unsigned short* ab = weff + (size_t)(dh*64 + rhalf*32 + l15)*CIN + i0*32 + g*8;
      bf16x8 af0 = *(const bf16x8*)(ab);
      bf16x8 af1 = *(const bf16x8*)(ab + 16*CIN);
      const unsigned char* rowb = stg + (hloc + dh)*7168 + g*1792;
      #pragma unroll
      for (int wt = 0; wt < 7; ++wt){
        const int w = wt*16 + l15;
        bf16x8 bfv = *(const bf16x8*)(rowb + ((w ^ (g & 3))*16));
        acc[0][wt] = __builtin_amdgcn_mfma_f32_16x16x32_bf16(af0, bfv, acc[0][wt], 0, 0, 0);
        acc[1][wt] = __builtin_amdgcn_mfma_f32_16x16x32_bf16(af1, bfv, acc[1][wt], 0, 0, 0);
      }
    }
  };

  LOADS(0);
  for (int t = 0; t < 8; ++t){
    __syncthreads();                 // stage buffer free (all waves done with t-1)
    WRITE();                         // convert + ds_write chunk t
    if (t < 7) LOADS(t+1);           // issue next chunk's loads (T14: hide under compute)
    __syncthreads();                 // staged chunk visible
    MSTEP(t);
  }
  __syncthreads();                   // phase A reads done before slab overlays

  // ---- phase B: acc -> LDS y2 slab [2 h][114 w'][72 pad] (bf16), w' = w+1 ----
  unsigned short* y2b = lds;
  if (tid < 32){
    int hh = tid >> 4, wsel = (tid >> 3) & 1, rq = tid & 7;
    *(uint4*)(y2b + hh*8208 + (wsel ? 113 : 0)*72 + rq*8) = (uint4){0,0,0,0};
  }
  #pragma unroll
  for (int wt = 0; wt < 7; ++wt){
    #pragma unroll
    for (int rt = 0; rt < 2; ++rt){
      unsigned lo = rne2(acc[rt][wt][0], acc[rt][wt][1]);
      unsigned hi = rne2(acc[rt][wt][2], acc[rt][wt][3]);
      uint2 st; st.x = lo; st.y = hi;
      *(uint2*)(y2b + hloc*8208 + (wt*16 + l15 + 1)*72 + rhalf*32 + rt*16 + g*4) = st;
    }
  }
  __syncthreads();

  // ---- phase C: tail GEMM, 4 passes of 32 o per wave ----
  const int h = h0 + hloc;
  #pragma unroll
  for (int opass = 0; opass < 4; ++opass){
    const int obase = rhalf*128 + opass*32;
    f32x4 a2[2][7];
    #pragma unroll
    for (int a = 0; a < 2; ++a)
      #pragma unroll
      for (int b = 0; b < 7; ++b) a2[a][b] = (f32x4){0.f,0.f,0.f,0.f};

    #pragma unroll
    for (int s = 0; s < 6; ++s){       // k-step: dw = s>>1, r-half = s&1
      bf16x8 afc[2];
      const unsigned short* ab = wtp + (size_t)(obase + l15)*192 + s*32 + g*8;
      #pragma unroll
      for (int rt = 0; rt < 2; ++rt)
        afc[rt] = *(const bf16x8*)(ab + rt*16*192);
      const unsigned short* qb = y2b + hloc*8208 + (l15 + (s >> 1))*72 + (s & 1)*32 + g*8;
      #pragma unroll
      for (int wt = 0; wt < 7; ++wt){
        bf16x8 bvv = *(const bf16x8*)(qb + wt*16*72);
        #pragma unroll
        for (int rt = 0; rt < 2; ++rt)
          a2[rt][wt] = __builtin_amdgcn_mfma_f32_16x16x32_bf16(afc[rt], bvv, a2[rt][wt], 0, 0, 0);
      }
    }

    float* ob = out + ((size_t)(bb*COUT) + obase)*HW_ + h*W_;
    #pragma unroll
    for (int rt = 0; rt < 2; ++rt){
      #pragma unroll
      for (int ii = 0; ii < 4; ++ii){
        float bvv = bias[obase + rt*16 + g*4 + ii];
        #pragma unroll
        for (int wt = 0; wt < 7; ++wt)
          ob[(size_t)(rt*16 + g*4 + ii)*HW_ + wt*16 + l15] = a2[rt][wt][ii] + bvv;
      }
    }
  }
}

extern "C" void kernel_launch(void* const* d_in, const int* in_sizes, int n_in,
                              void* d_out, int out_size, void* d_ws, size_t ws_size,
                              hipStream_t stream) {
  const float* x      = (const float*)d_in[0];
  const float* w_head = (const float*)d_in[1];
  const float* w_body = (const float*)d_in[2];
  const float* w_tail = (const float*)d_in[3];
  const float* b_tail = (const float*)d_in[4];
  float* out = (float*)d_out;
  char* ws = (char*)d_ws;

  // ws: wsum fp32 @0 (262144 B); weff bf16 @262144 (98304 B); wtp bf16 @360448 (98304 B)
  float*          wsum = (float*)ws;
  unsigned short* weff = (unsigned short*)(ws + 262144);
  unsigned short* wtp  = (unsigned short*)(ws + 360448);

  k_wsum<<<256, 256, 0, stream>>>(w_head, wsum);
  k_pre2<<<448, 256, 0, stream>>>(w_body, wsum, weff, w_tail, wtp);
  // grid 896 divisible by 8: bijective XCD swizzle, cpx = 896/8 = 112
  k_all <<<896, 256, 0, stream>>>(x, weff, wtp, b_tail, out, 112u);
}

// Round 14
// 161.985 us; speedup vs baseline: 1.1350x; 1.0024x over previous
//
#include <hip/hip_runtime.h>
#include <stdint.h>

#define CIN 256
#define COUT 256
#define RANK 64
#define H_ 112
#define W_ 112
#define HW_ (112*112)

typedef short bf16x8 __attribute__((ext_vector_type(8)));   // 8 bf16 = 4 VGPRs
typedef float f32x4 __attribute__((ext_vector_type(4)));

__device__ __forceinline__ unsigned short rne1(float a){
  unsigned ua = __builtin_bit_cast(unsigned, a);
  ua += 0x7FFFu + ((ua >> 16) & 1u);
  return (unsigned short)(ua >> 16);
}
// packed fp32x2 -> bf16x2 (lo = a, hi = b), single VALU op
__device__ __forceinline__ unsigned cvtpk(float a, float b){
  unsigned r;
  asm("v_cvt_pk_bf16_f32 %0, %1, %2" : "=v"(r) : "v"(a), "v"(b));
  return r;
}

// ---- K0a: w_sum[o][i] = sum_k w_head[k][o][i] ----
__global__ __launch_bounds__(256) void k_wsum(const float* __restrict__ wh,
                                              float* __restrict__ wsum){
  int o = blockIdx.x, i = threadIdx.x;
  float s = 0.f;
  for (int k = 0; k < RANK; ++k) s += wh[(k*COUT + o)*CIN + i];
  wsum[o*CIN + i] = s;
}

// ---- K0b: blocks [0,192): w_eff[dh][r][i] (bf16); blocks [192,448): wtp[o][dw][r] (bf16)
__global__ __launch_bounds__(256) void k_pre2(const float* __restrict__ wb,
                                              const float* __restrict__ wsum,
                                              unsigned short* __restrict__ weff,
                                              const float* __restrict__ wt,
                                              unsigned short* __restrict__ wtp){
  const int tid = threadIdx.x;
  if (blockIdx.x < 192){
    int bid = blockIdx.x;            // dh*64 + r
    int dh = bid >> 6, r = bid & 63;
    float s = 0.f;
    for (int o = 0; o < COUT; ++o)
      s += wb[(r*COUT + o)*3 + dh] * wsum[o*CIN + tid];
    weff[bid*CIN + tid] = rne1(s);
  } else {
    int o = blockIdx.x - 192;
    if (tid < 192){
      int dw = tid >> 6, r = tid & 63;
      wtp[o*192 + tid] = rne1(wt[(o*RANK + r)*3 + dw]);
    }
  }
}

// ---- K_all: x fp32 -> in-kernel bf16 transpose-stage -> body GEMM -> LDS y2
//             -> tail GEMM -> out. Depth-2 counted-vmcnt pipeline, split barriers.
// Stage layout per step: [4 rows][4 g][112 slots][8 c] bf16, slot = w^(g&3)^((w>>2)&3)
// (bank-conflict-free: writes 1 lane/bank per half-wave; b128 reads spread per octet).
__global__ __launch_bounds__(256,2) void k_all(const float* __restrict__ x,
                                               const unsigned short* __restrict__ weff,
                                               const unsigned short* __restrict__ wtp,
                                               const float* __restrict__ bias,
                                               float* __restrict__ out,
                                               unsigned cpx){
  __shared__ alignas(16) unsigned short lds[16416];  // 32832 B: stage (28672) / y2 slab
  const int tid  = threadIdx.x;
  const int wid  = tid >> 6, lane = tid & 63, g = lane >> 4, l15 = lane & 15;
  const unsigned orig = blockIdx.x;
  const unsigned wg   = (orig & 7u)*cpx + (orig >> 3);   // bijective XCD swizzle
  const int bb   = wg / 56, hb = wg % 56;
  const int h0   = hb*2;
  const int hloc = wid >> 1, rhalf = wid & 1;

  // staging lane roles: q_st = w-quad, cpair = channel pair 0..15
  const int q_st = lane & 3, cpair = lane >> 2;
  const int g_st = cpair >> 2, cp3 = cpair & 3;
  const int grow = h0 - 1 + wid;
  const bool rok = (grow >= 0) && (grow < H_);
  const float* xrow = x + ((size_t)bb*CIN + cpair*2)*HW_ + (size_t)(rok ? grow : 0)*W_;
  unsigned char* const stg = (unsigned char*)lds;
  const int cxor = (g_st ^ q_st) & 3;                  // write slot XOR (see header)
  const int lxor = (l15 ^ (g & 3) ^ ((l15 >> 2) & 3)); // read slot low bits, per-lane const

  // ---- phase A: 8 steps x 32 ch; depth-2 reg pipeline ----
  f32x4 acc[2][7];
  #pragma unroll
  for (int a = 0; a < 2; ++a)
    #pragma unroll
    for (int b = 0; b < 7; ++b) acc[a][b] = (f32x4){0.f,0.f,0.f,0.f};

  f32x4  xa[2][7], xb[2][7];      // x fp32 in-flight, 2 sets
  bf16x8 afp[2][3][2];            // weff A-frags, 2 sets

  auto ISSUE = [&](int t){        // issue pair t: A-frags first, then x (in-order!)
    const int s = t & 1;
    #pragma unroll
    for (int dh = 0; dh < 3; ++dh){
      const unsigned short* ab = weff + (size_t)(dh*64 + rhalf*32 + l15)*CIN + t*32 + g*8;
      afp[s][dh][0] = *(const bf16x8*)(ab);
      afp[s][dh][1] = *(const bf16x8*)(ab + 16*CIN);
    }
    const float* pa = xrow + (size_t)t*32*HW_;
    #pragma unroll
    for (int j = 0; j < 7; ++j){
      const int w0 = 16*j + q_st*4;
      if (rok){
        xa[s][j] = *(const f32x4*)(pa + w0);
        xb[s][j] = *(const f32x4*)(pa + HW_ + w0);
      } else {
        xa[s][j] = (f32x4){0.f,0.f,0.f,0.f};
        xb[s][j] = (f32x4){0.f,0.f,0.f,0.f};
      }
    }
  };
  auto WRITE = [&](int t){
    const int s = t & 1;
    unsigned char* base = stg + wid*7168 + g_st*1792 + cp3*4;
    #pragma unroll
    for (int j = 0; j < 7; ++j){
      const int w0 = 16*j + q_st*4;
      #pragma unroll
      for (int k = 0; k < 4; ++k){
        unsigned pk = cvtpk(xa[s][j][k], xb[s][j][k]);
        *(unsigned*)(base + (unsigned)(w0*16) + (unsigned)((k ^ cxor) << 4)) = pk;
      }
    }
  };
  auto MSTEP = [&](int t){
    const int s = t & 1;
    #pragma unroll
    for (int dh = 0; dh < 3; ++dh){
      const unsigned char* rowb = stg + (hloc + dh)*7168 + g*1792 + lxor*16;
      #pragma unroll
      for (int wt = 0; wt < 7; ++wt){
        bf16x8 bfv = *(const bf16x8*)(rowb + wt*256);
        acc[0][wt] = __builtin_amdgcn_mfma_f32_16x16x32_bf16(afp[s][dh][0], bfv, acc[0][wt], 0, 0, 0);
        acc[1][wt] = __builtin_amdgcn_mfma_f32_16x16x32_bf16(afp[s][dh][1], bfv, acc[1][wt], 0, 0, 0);
      }
    }
  };

  ISSUE(0); ISSUE(1);
  #pragma unroll
  for (int t = 0; t < 8; ++t){
    // retire pair t (A+x, 20 ops), leave pair t+1 (20) in flight
    if (t < 7) asm volatile("s_waitcnt vmcnt(20)" ::: "memory");
    else       asm volatile("s_waitcnt vmcnt(0)"  ::: "memory");
    WRITE(t);
    asm volatile("s_waitcnt lgkmcnt(0)" ::: "memory");   // ds_writes visible...
    __builtin_amdgcn_s_barrier();                        // ...to all waves; vm survives
    MSTEP(t);
    if (t < 6) ISSUE(t + 2);                             // reuse set t&1 (freed)
    __builtin_amdgcn_s_barrier();                        // reads done before next WRITE
  }

  // ---- phase B: acc -> LDS y2 slab [2 h][114 w'][72 pad] (bf16), w' = w+1 ----
  unsigned short* y2b = lds;
  if (tid < 32){
    int hh = tid >> 4, wsel = (tid >> 3) & 1, rq = tid & 7;
    *(uint4*)(y2b + hh*8208 + (wsel ? 113 : 0)*72 + rq*8) = (uint4){0,0,0,0};
  }
  #pragma unroll
  for (int wt = 0; wt < 7; ++wt){
    #pragma unroll
    for (int rt = 0; rt < 2; ++rt){
      uint2 st;
      st.x = cvtpk(acc[rt][wt][0], acc[rt][wt][1]);
      st.y = cvtpk(acc[rt][wt][2], acc[rt][wt][3]);
      *(uint2*)(y2b + hloc*8208 + (wt*16 + l15 + 1)*72 + rhalf*32 + rt*16 + g*4) = st;
    }
  }
  __syncthreads();

  // ---- phase C: tail GEMM, 4 passes of 32 o per wave ----
  const int h = h0 + hloc;
  #pragma unroll
  for (int opass = 0; opass < 4; ++opass){
    const int obase = rhalf*128 + opass*32;
    f32x4 a2[2][7];
    #pragma unroll
    for (int a = 0; a < 2; ++a)
      #pragma unroll
      for (int b = 0; b < 7; ++b) a2[a][b] = (f32x4){0.f,0.f,0.f,0.f};

    #pragma unroll
    for (int s = 0; s < 6; ++s){       // k-step: dw = s>>1, r-half = s&1
      bf16x8 afc[2];
      const unsigned short* ab = wtp + (size_t)(obase + l15)*192 + s*32 + g*8;
      #pragma unroll
      for (int rt = 0; rt < 2; ++rt)
        afc[rt] = *(const bf16x8*)(ab + rt*16*192);
      const unsigned short* qb = y2b + hloc*8208 + (l15 + (s >> 1))*72 + (s & 1)*32 + g*8;
      #pragma unroll
      for (int wt = 0; wt < 7; ++wt){
        bf16x8 bvv = *(const bf16x8*)(qb + wt*16*72);
        #pragma unroll
        for (int rt = 0; rt < 2; ++rt)
          a2[rt][wt] = __builtin_amdgcn_mfma_f32_16x16x32_bf16(afc[rt], bvv, a2[rt][wt], 0, 0, 0);
      }
    }

    float* ob = out + ((size_t)(bb*COUT) + obase)*HW_ + h*W_;
    #pragma unroll
    for (int rt = 0; rt < 2; ++rt){
      #pragma unroll
      for (int ii = 0; ii < 4; ++ii){
        float bvv = bias[obase + rt*16 + g*4 + ii];
        #pragma unroll
        for (int wt = 0; wt < 7; ++wt)
          ob[(size_t)(rt*16 + g*4 + ii)*HW_ + wt*16 + l15] = a2[rt][wt][ii] + bvv;
      }
    }
  }
}

extern "C" void kernel_launch(void* const* d_in, const int* in_sizes, int n_in,
                              void* d_out, int out_size, void* d_ws, size_t ws_size,
                              hipStream_t stream) {
  const float* x      = (const float*)d_in[0];
  const float* w_head = (const float*)d_in[1];
  const float* w_body = (const float*)d_in[2];
  const float* w_tail = (const float*)d_in[3];
  const float* b_tail = (const float*)d_in[4];
  float* out = (float*)d_out;
  char* ws = (char*)d_ws;

  // ws: wsum fp32 @0 (262144 B); weff bf16 @262144 (98304 B); wtp bf16 @360448 (98304 B)
  float*          wsum = (float*)ws;
  unsigned short* weff = (unsigned short*)(ws + 262144);
  unsigned short* wtp  = (unsigned short*)(ws + 360448);

  k_wsum<<<256, 256, 0, stream>>>(w_head, wsum);
  k_pre2<<<448, 256, 0, stream>>>(w_body, wsum, weff, w_tail, wtp);
  k_all <<<896, 256, 0, stream>>>(x, weff, wtp, b_tail, out, 112u);
}